// Round 10
// baseline (936.922 us; speedup 1.0000x reference)
//
#include <hip/hip_runtime.h>
#include <hip/hip_bf16.h>
#include <math.h>

// R9->R10: k2 = dense inner (8 rows/thread) at 512-block grid (R9's 256-block grid was
// the regression: 21% occ). k3/k_stats eliminated: C recomputed in k2/k4 prologues from
// double-buffered wsum; BN stats via atomicAdd accumulators + in-consumer recompute.
// 17 launches (was 29).

#define NPIX 1048576.f

// ---------------- K0: combined input weights + zero stat accumulators ----------------
__global__ void k0_prep(const float* __restrict__ Wr, const float* __restrict__ Wi,
                        const float* __restrict__ pr, const float* __restrict__ pi,
                        float* __restrict__ ArT, float* __restrict__ AiT,
                        float* __restrict__ accs) {
    int w  = blockIdx.x;    // 0..63
    int w2 = threadIdx.x;   // 0..255
    float p0r = pr[0], p1r = pr[1], p0i = pi[0], p1i = pi[1];
    float wr0 = Wr[w2 * 64 + w],         wi0 = Wi[w2 * 64 + w];
    float wr1 = Wr[(256 + w2) * 64 + w], wi1 = Wi[(256 + w2) * 64 + w];
    ArT[w * 256 + w2] = p0r * wr0 - p0i * wi0 + p1r * wr1 - p1i * wi1;
    AiT[w * 256 + w2] = p0r * wi0 + p0i * wr0 + p1r * wi1 + p1i * wr1;
    if (w == 0 && w2 < 64) accs[w2] = 0.f;   // accC1[32] + accC2[32]
}

// ---------------- K0b: transpose the 8 branch matrices ----------------
__global__ void k0b_T(const float* __restrict__ Wmr, const float* __restrict__ Wmi,
                      float* __restrict__ WmrT, float* __restrict__ WmiT) {
    int m = blockIdx.x;
    int t = threadIdx.x;
    const float* sr = Wmr + m * 4096;
    const float* si = Wmi + m * 4096;
    float* dr = WmrT + m * 4096;
    float* di = WmiT + m * 4096;
    for (int k = t; k < 4096; k += 256) {
        int c = k >> 6, h = k & 63;
        dr[h * 64 + c] = sr[k];
        di[h * 64 + c] = si[k];
    }
}

// ---------------- K1: G projection ----------------
__global__ __launch_bounds__(256) void k1_G(const float* __restrict__ inp,
                                            const float* __restrict__ ArT,
                                            const float* __restrict__ AiT,
                                            float* __restrict__ Gr, float* __restrict__ Gi) {
    int hc = blockIdx.x;
    int b  = blockIdx.y;
    int t  = threadIdx.x;
    __shared__ float sxr[8][64], sxi[8][64];
    int base_r = (b * 2 + 0) * 4096 + hc * 8 * 64;
    int base_i = (b * 2 + 1) * 4096 + hc * 8 * 64;
    for (int k = t; k < 512; k += 256) {
        int r = k >> 6, w = k & 63;
        sxr[r][w] = inp[base_r + r * 64 + w];
        sxi[r][w] = inp[base_i + r * 64 + w];
    }
    __syncthreads();
    float accr[8], acci[8];
#pragma unroll
    for (int r = 0; r < 8; r++) { accr[r] = 0.f; acci[r] = 0.f; }
    for (int k = 0; k < 64; k++) {
        float ar = ArT[k * 256 + t], ai = AiT[k * 256 + t];
#pragma unroll
        for (int r = 0; r < 8; r++) {
            float xr = sxr[r][k], xi = sxi[r][k];
            accr[r] += xr * ar - xi * ai;
            acci[r] += xi * ar + xr * ai;
        }
    }
#pragma unroll
    for (int r = 0; r < 8; r++) {
        int h = hc * 8 + r;
        Gr[(b * 64 + h) * 256 + t] = accr[r];
        Gi[(b * 64 + h) * 256 + t] = acci[r];
    }
}

// ---------------- K2: one branch, C-prologue, 8 rows/thread ----------------
__global__ __launch_bounds__(512) void k2_layer(const float* __restrict__ Gr,
                                                const float* __restrict__ Gi,
                                                const float2* __restrict__ wsumIn,
                                                float2* __restrict__ wsumOut,
                                                const float* __restrict__ Wmr,
                                                const float* __restrict__ Wmi,
                                                const float* __restrict__ WmrT,
                                                const float* __restrict__ WmiT,
                                                const float* __restrict__ Wcr,
                                                const float* __restrict__ Wci,
                                                int layer) {
    int wc = blockIdx.x;  // 4 column chunks of 64
    int j  = blockIdx.y;  // branch
    int b  = blockIdx.z;
    int t = threadIdx.x, tx = t & 63;
    int h0 = __builtin_amdgcn_readfirstlane((t >> 6) << 3);  // wave-uniform: 8 rows/wave
    __shared__ float2 sX[4096];   // [h][w] C*G, reused for E after sync
    __shared__ float2 sC[64];

    // --- C prologue (was k3): combine previous layer's wsum ---
    if (layer == 0) {
        if (t < 64) sC[t] = make_float2(1.f, 0.f);
    } else if (t < 64) {
        float accr = 0.f, acci = 0.f;
#pragma unroll
        for (int jj = 0; jj < 2; jj++) {
            float wr = 0.f, wi = 0.f;
#pragma unroll
            for (int q = 0; q < 4; q++) {
                float2 p = wsumIn[((b * 64 + t) * 2 + jj) * 4 + q];
                wr += p.x; wi += p.y;
            }
            float m2 = wr * wr + wi * wi;
            float cr = 1.f, ci = 0.f;
            if (m2 > 0.f) { float inv = 1.f / sqrtf(m2); cr = wr * inv; ci = -wi * inv; }
            float wcr = Wcr[(layer - 1) * 2 + jj], wci = Wci[(layer - 1) * 2 + jj];
            accr += cr * wcr - ci * wci;
            acci += ci * wcr + cr * wci;
        }
        sC[t] = make_float2(accr, acci);
    }
    __syncthreads();

    int gbase = b * 16384 + wc * 64 + tx;
    float gr_[8], gi_[8];
#pragma unroll
    for (int r = 0; r < 8; r++) {
        int h = h0 + r;
        float gr = Gr[gbase + h * 256], gi = Gi[gbase + h * 256];
        gr_[r] = gr; gi_[r] = gi;
        float2 c = sC[h];
        sX[h * 64 + tx] = make_float2(c.x * gr - c.y * gi, c.x * gi + c.y * gr);
    }
    __syncthreads();

    int mat = layer + 4 * j;
    const float* Wr0  = Wmr  + mat * 4096 + h0 * 64;  // I: rows c=h0.., contiguous in h
    const float* Wi0  = Wmi  + mat * 4096 + h0 * 64;
    const float* WrT0 = WmrT + mat * 4096 + h0 * 64;  // Z: rows h=h0.., contiguous in c
    const float* WiT0 = WmiT + mat * 4096 + h0 * 64;

    // I[c][tx], c = h0+r : 1 ds_read_b64 feeds 32 FMA
    float Ir[8] = {0,0,0,0,0,0,0,0}, Ii[8] = {0,0,0,0,0,0,0,0};
#pragma unroll 4
    for (int h = 0; h < 64; h++) {
        float2 x = sX[h * 64 + tx];
#pragma unroll
        for (int r = 0; r < 8; r++) {
            float wr = Wr0[r * 64 + h], wi = Wi0[r * 64 + h];
            Ir[r] += wr * x.x - wi * x.y;
            Ii[r] += wr * x.y + wi * x.x;
        }
    }
    __syncthreads();  // all sX reads done
    // E = (1+log|I|^2)*conj(I) into sX as [c][w]
#pragma unroll
    for (int r = 0; r < 8; r++) {
        float m2 = Ir[r] * Ir[r] + Ii[r] * Ii[r];
        float s = 1.f + __logf(m2);
        sX[(h0 + r) * 64 + tx] = make_float2(s * Ir[r], -s * Ii[r]);
    }
    __syncthreads();

    // Z[h][tx], h = h0+r
    float Zr[8] = {0,0,0,0,0,0,0,0}, Zi[8] = {0,0,0,0,0,0,0,0};
#pragma unroll 4
    for (int c = 0; c < 64; c++) {
        float2 e = sX[c * 64 + tx];
#pragma unroll
        for (int r = 0; r < 8; r++) {
            float wr = WrT0[r * 64 + c], wi = WiT0[r * 64 + c];
            Zr[r] += wr * e.x - wi * e.y;
            Zi[r] += wr * e.y + wi * e.x;
        }
    }
    // partial w-sum over this 64-column chunk
#pragma unroll
    for (int r = 0; r < 8; r++) {
        int h = h0 + r;
        float pr = gr_[r] * Zr[r] - gi_[r] * Zi[r];
        float pi = gr_[r] * Zi[r] + gi_[r] * Zr[r];
#pragma unroll
        for (int off = 32; off > 0; off >>= 1) {
            pr += __shfl_xor(pr, off);
            pi += __shfl_xor(pi, off);
        }
        if (tx == 0) wsumOut[((b * 64 + h) * 2 + j) * 4 + wc] = make_float2(pr, pi);
    }
}

// ---------------- K4: final projection + block max (C-prologue) ----------------
__global__ __launch_bounds__(1024) void k4_proj(const float* __restrict__ Gr,
                                                const float* __restrict__ Gi,
                                                const float2* __restrict__ wsumIn,
                                                const float* __restrict__ Wcr,
                                                const float* __restrict__ Wci,
                                                const float* __restrict__ W3r,
                                                const float* __restrict__ W3i,
                                                float* __restrict__ xmag,
                                                float* __restrict__ pmax) {
    int wc = blockIdx.x;   // 4 col chunks
    int cb = blockIdx.y;   // 2 c-halves
    int b  = blockIdx.z;
    int t = threadIdx.x, tx = t & 63, ty = t >> 6;  // ty 0..15
    __shared__ float2 sX[4096];
    __shared__ float2 sC[64];
    if (t < 64) {  // C after layer 3 (Wc[3])
        float accr = 0.f, acci = 0.f;
#pragma unroll
        for (int jj = 0; jj < 2; jj++) {
            float wr = 0.f, wi = 0.f;
#pragma unroll
            for (int q = 0; q < 4; q++) {
                float2 p = wsumIn[((b * 64 + t) * 2 + jj) * 4 + q];
                wr += p.x; wi += p.y;
            }
            float m2 = wr * wr + wi * wi;
            float cr = 1.f, ci = 0.f;
            if (m2 > 0.f) { float inv = 1.f / sqrtf(m2); cr = wr * inv; ci = -wi * inv; }
            float wcr = Wcr[6 + jj], wci = Wci[6 + jj];
            accr += cr * wcr - ci * wci;
            acci += ci * wcr + cr * wci;
        }
        sC[t] = make_float2(accr, acci);
    }
    __syncthreads();
    int c0 = __builtin_amdgcn_readfirstlane(ty << 2);
    const float* W3r0 = W3r + (cb * 64 + c0) * 64;
    const float* W3i0 = W3i + (cb * 64 + c0) * 64;
    int gbase = b * 16384 + wc * 64 + tx;
#pragma unroll
    for (int r = 0; r < 4; r++) {
        int h = (ty << 2) + r;
        float gr = Gr[gbase + h * 256], gi = Gi[gbase + h * 256];
        float2 c = sC[h];
        sX[h * 64 + tx] = make_float2(c.x * gr - c.y * gi, c.x * gi + c.y * gr);
    }
    __syncthreads();
    float Fr[4] = {0,0,0,0}, Fi[4] = {0,0,0,0};
#pragma unroll 8
    for (int h = 0; h < 64; h++) {
        float2 x = sX[h * 64 + tx];
#pragma unroll
        for (int r = 0; r < 4; r++) {
            float wr = W3r0[r * 64 + h], wi = W3i0[r * 64 + h];
            Fr[r] += wr * x.x - wi * x.y;
            Fi[r] += wr * x.y + wi * x.x;
        }
    }
    float mx = 0.f;
#pragma unroll
    for (int r = 0; r < 4; r++) {
        int cl = (ty << 2) + r;
        float mag = sqrtf(Fr[r] * Fr[r] + Fi[r] * Fi[r]);
        xmag[(b * 128 + cb * 64 + cl) * 256 + wc * 64 + tx] = mag;
        mx = fmaxf(mx, mag);
    }
#pragma unroll
    for (int off = 32; off > 0; off >>= 1) mx = fmaxf(mx, __shfl_xor(mx, off));
    __syncthreads();
    float* scratch = (float*)sX;
    if (tx == 0) scratch[ty] = mx;
    __syncthreads();
    if (t == 0) {
        float m = scratch[0];
#pragma unroll
        for (int k = 1; k < 16; k++) m = fmaxf(m, scratch[k]);
        pmax[b * 8 + cb * 4 + wc] = m;
    }
}

// ---------------- conv1 fused: tap = scale(x) [L0] or relu(x + bn2(h2)) [L1-3] --------
__global__ __launch_bounds__(256) void k_conv1f(const float* __restrict__ xin,
                                                const float* __restrict__ h2,
                                                const float* __restrict__ cw,
                                                const float* __restrict__ bn2g,
                                                const float* __restrict__ bn2b,
                                                const float* __restrict__ accC2,
                                                const float* __restrict__ pmax,
                                                float* __restrict__ hout,
                                                float* __restrict__ xout,
                                                float* __restrict__ accC1,
                                                int layer) {
    int hb = blockIdx.x;  // 16 row chunks of 4
    int co = blockIdx.y;
    int b  = blockIdx.z;
    int tx = threadIdx.x;
    float wgt[18];
    const float* wp = cw + layer * 36 + co * 18;
#pragma unroll
    for (int k = 0; k < 18; k++) wgt[k] = wp[k];
    float sc0 = 0.f, sc1 = 0.f, sh0 = 0.f, sh1 = 0.f, inv = 1.f;
    if (layer == 0) {
        float m = 0.f;
#pragma unroll
        for (int k = 0; k < 8; k++) m = fmaxf(m, pmax[b * 8 + k]);
        inv = 1.f / m;
    } else {
        int pl = layer - 1;
        float s0 = accC2[pl * 4 + 0], s1 = accC2[pl * 4 + 1];
        float q0 = accC2[pl * 4 + 2], q1 = accC2[pl * 4 + 3];
        float mu0 = s0 / NPIX, mu1 = s1 / NPIX;
        float rs0 = rsqrtf(q0 / NPIX - mu0 * mu0 + 1e-5f);
        float rs1 = rsqrtf(q1 / NPIX - mu1 * mu1 + 1e-5f);
        sc0 = rs0 * bn2g[pl * 2 + 0]; sh0 = bn2b[pl * 2 + 0] - mu0 * sc0;
        sc1 = rs1 * bn2g[pl * 2 + 1]; sh1 = bn2b[pl * 2 + 1] - mu1 * sc1;
    }
    int wm = (tx + 255) & 255, wpp = (tx + 1) & 255;
    float lsum = 0.f, lsq = 0.f;
    for (int r = 0; r < 4; r++) {
        int hh = hb * 4 + r;
        int hm = (hh + 63) & 63, hp = (hh + 1) & 63;
        const int rows[3] = {hm, hh, hp};
        const int cols[3] = {wm, tx, wpp};
        float acc = 0.f;
#pragma unroll
        for (int ci = 0; ci < 2; ci++) {
            const float* xp  = xin + (b * 2 + ci) * 16384;
            const float* hp2 = h2  + (b * 2 + ci) * 16384;
            float sc = ci ? sc1 : sc0, sh = ci ? sh1 : sh0;
            const float* wg = wgt + ci * 9;
#pragma unroll
            for (int kh = 0; kh < 3; kh++)
#pragma unroll
                for (int kw = 0; kw < 3; kw++) {
                    int idx = rows[kh] * 256 + cols[kw];
                    float v;
                    if (layer == 0) v = xp[idx] * inv;
                    else            v = fmaxf(xp[idx] + hp2[idx] * sc + sh, 0.f);
                    if (ci == co && kh == 1 && kw == 1)
                        xout[(b * 2 + co) * 16384 + hh * 256 + tx] = v;
                    acc += wg[kh * 3 + kw] * v;
                }
        }
        hout[((b * 2 + co) * 64 + hh) * 256 + tx] = acc;
        lsum += acc; lsq += acc * acc;
    }
#pragma unroll
    for (int off = 32; off > 0; off >>= 1) {
        lsum += __shfl_xor(lsum, off);
        lsq  += __shfl_xor(lsq, off);
    }
    __shared__ float ssum[4], ssq[4];
    int tyy = tx >> 6, lane = tx & 63;
    if (lane == 0) { ssum[tyy] = lsum; ssq[tyy] = lsq; }
    __syncthreads();
    if (tx == 0) {
        atomicAdd(&accC1[layer * 4 + co],     ssum[0] + ssum[1] + ssum[2] + ssum[3]);
        atomicAdd(&accC1[layer * 4 + 2 + co], ssq[0] + ssq[1] + ssq[2] + ssq[3]);
    }
}

// ---------------- conv2: bn1+relu on taps; atomic stats out ----------------
__global__ __launch_bounds__(256) void k_conv2(const float* __restrict__ h1,
                                               const float* __restrict__ cw,
                                               const float* __restrict__ bn1g,
                                               const float* __restrict__ bn1b,
                                               const float* __restrict__ accC1,
                                               float* __restrict__ hout,
                                               float* __restrict__ accC2,
                                               int layer) {
    int hb = blockIdx.x;
    int co = blockIdx.y;
    int b  = blockIdx.z;
    int tx = threadIdx.x;
    float wgt[18];
    const float* wp = cw + layer * 36 + co * 18;
#pragma unroll
    for (int k = 0; k < 18; k++) wgt[k] = wp[k];
    float s0 = accC1[layer * 4 + 0], s1 = accC1[layer * 4 + 1];
    float q0 = accC1[layer * 4 + 2], q1 = accC1[layer * 4 + 3];
    float mu0 = s0 / NPIX, mu1 = s1 / NPIX;
    float rs0 = rsqrtf(q0 / NPIX - mu0 * mu0 + 1e-5f);
    float rs1 = rsqrtf(q1 / NPIX - mu1 * mu1 + 1e-5f);
    float sc0 = rs0 * bn1g[layer * 2 + 0], sh0 = bn1b[layer * 2 + 0] - mu0 * sc0;
    float sc1 = rs1 * bn1g[layer * 2 + 1], sh1 = bn1b[layer * 2 + 1] - mu1 * sc1;
    int wm = (tx + 255) & 255, wpp = (tx + 1) & 255;
    float lsum = 0.f, lsq = 0.f;
    for (int r = 0; r < 4; r++) {
        int hh = hb * 4 + r;
        int hm = (hh + 63) & 63, hp = (hh + 1) & 63;
        const int rows[3] = {hm, hh, hp};
        const int cols[3] = {wm, tx, wpp};
        float acc = 0.f;
#pragma unroll
        for (int ci = 0; ci < 2; ci++) {
            const float* xp = h1 + (b * 2 + ci) * 16384;
            float sc = ci ? sc1 : sc0, sh = ci ? sh1 : sh0;
            const float* wg = wgt + ci * 9;
#pragma unroll
            for (int kh = 0; kh < 3; kh++)
#pragma unroll
                for (int kw = 0; kw < 3; kw++) {
                    float v = fmaxf(xp[rows[kh] * 256 + cols[kw]] * sc + sh, 0.f);
                    acc += wg[kh * 3 + kw] * v;
                }
        }
        hout[((b * 2 + co) * 64 + hh) * 256 + tx] = acc;
        lsum += acc; lsq += acc * acc;
    }
#pragma unroll
    for (int off = 32; off > 0; off >>= 1) {
        lsum += __shfl_xor(lsum, off);
        lsq  += __shfl_xor(lsq, off);
    }
    __shared__ float ssum[4], ssq[4];
    int tyy = tx >> 6, lane = tx & 63;
    if (lane == 0) { ssum[tyy] = lsum; ssq[tyy] = lsq; }
    __syncthreads();
    if (tx == 0) {
        atomicAdd(&accC2[layer * 4 + co],     ssum[0] + ssum[1] + ssum[2] + ssum[3]);
        atomicAdd(&accC2[layer * 4 + 2 + co], ssq[0] + ssq[1] + ssq[2] + ssq[3]);
    }
}

// ---------------- K9: transposed conv; final residual + bn2(L3) inline ----------------
__global__ void k9_out(const float* __restrict__ x3, const float* __restrict__ h2,
                       const float* __restrict__ accC2,
                       const float* __restrict__ bn2g, const float* __restrict__ bn2b,
                       const float* __restrict__ Wout, float* __restrict__ out) {
    const int TOT = 64 * 257 * 1025;
    int id = blockIdx.x * 256 + threadIdx.x;
    if (id >= TOT) return;
    float s0 = accC2[12], s1 = accC2[13], q0 = accC2[14], q1 = accC2[15];
    float mu0 = s0 / NPIX, mu1 = s1 / NPIX;
    float rs0 = rsqrtf(q0 / NPIX - mu0 * mu0 + 1e-5f);
    float rs1 = rsqrtf(q1 / NPIX - mu1 * mu1 + 1e-5f);
    float sc0 = rs0 * bn2g[6], sh0 = bn2b[6] - mu0 * sc0;
    float sc1 = rs1 * bn2g[7], sh1 = bn2b[7] - mu1 * sc1;
    int b   = id / 263425;
    int rem = id - b * 263425;
    int oh  = rem / 1025;
    int ow  = rem - oh * 1025;
    int kh0 = (5 - oh) & 3;
    int kw0 = (5 - ow) & 3;
    float acc = 0.f;
#pragma unroll
    for (int ah = 0; ah < 2; ah++) {
        int kh = kh0 + 4 * ah;
        int d = oh + kh - 5;
        if (d < 0 || d > 252) continue;
        int rh = d >> 2;
#pragma unroll
        for (int aw = 0; aw < 2; aw++) {
            int kw = kw0 + 4 * aw;
            int e = ow + kw - 5;
            if (e < 0 || e > 1020) continue;
            int rw = e >> 2;
#pragma unroll
            for (int ci = 0; ci < 2; ci++) {
                int idx = ((b * 2 + ci) * 64 + rh) * 256 + rw;
                float v = fmaxf(x3[idx] + h2[idx] * (ci ? sc1 : sc0) + (ci ? sh1 : sh0), 0.f);
                acc += Wout[ci * 64 + (7 - kh) * 8 + (7 - kw)] * v;
            }
        }
    }
    out[id] = acc;
}

extern "C" void kernel_launch(void* const* d_in, const int* in_sizes, int n_in,
                              void* d_out, int out_size, void* d_ws, size_t ws_size,
                              hipStream_t stream) {
    const float* inp   = (const float*)d_in[0];
    const float* Winr  = (const float*)d_in[1];
    const float* Wini  = (const float*)d_in[2];
    const float* Wprer = (const float*)d_in[3];
    const float* Wprei = (const float*)d_in[4];
    const float* Wmr   = (const float*)d_in[5];
    const float* Wmi   = (const float*)d_in[6];
    const float* Wcr   = (const float*)d_in[7];
    const float* Wci   = (const float*)d_in[8];
    const float* W3r   = (const float*)d_in[9];
    const float* W3i   = (const float*)d_in[10];
    const float* cw1   = (const float*)d_in[11];
    const float* bn1g  = (const float*)d_in[12];
    const float* bn1b  = (const float*)d_in[13];
    const float* cw2   = (const float*)d_in[14];
    const float* bn2g  = (const float*)d_in[15];
    const float* bn2b  = (const float*)d_in[16];
    const float* Wout  = (const float*)d_in[17];
    float* out = (float*)d_out;

    float* ws = (float*)d_ws;
    float*  ArT   = ws;                         // 16384
    float*  AiT   = ArT + 16384;                // 16384
    float*  Gr    = AiT + 16384;                // 1048576
    float*  Gi    = Gr + 1048576;               // 1048576
    float2* wsum0 = (float2*)(Gi + 1048576);    // 32768 f2
    float2* wsum1 = wsum0 + 32768;              // 32768 f2
    float*  xmag  = (float*)(wsum1 + 32768);    // 2097152
    float*  h2    = xmag + 2097152;             // 2097152
    float*  pmax  = h2 + 2097152;               // 512
    float*  accC1 = pmax + 512;                 // 32
    float*  accC2 = accC1 + 32;                 // 32
    float*  h1    = Gr;   // overlay: G dead after k4_proj
    float*  WmrT  = h2;   // overlay: dead before conv section writes h2
    float*  WmiT  = h2 + 32768;
    float*  outS  = out;  // d_out as scratch until k9

    k0_prep<<<64, 256, 0, stream>>>(Winr, Wini, Wprer, Wprei, ArT, AiT, accC1);
    k0b_T<<<8, 256, 0, stream>>>(Wmr, Wmi, WmrT, WmiT);
    k1_G<<<dim3(8, 64), 256, 0, stream>>>(inp, ArT, AiT, Gr, Gi);
    // layer i: reads wsum[(i-1)&1], writes wsum[i&1]
    float2* wsb[2] = {wsum0, wsum1};
    for (int i = 0; i < 4; i++) {
        k2_layer<<<dim3(4, 2, 64), 512, 0, stream>>>(Gr, Gi, wsb[(i + 1) & 1], wsb[i & 1],
                                                     Wmr, Wmi, WmrT, WmiT, Wcr, Wci, i);
    }
    k4_proj<<<dim3(4, 2, 64), 1024, 0, stream>>>(Gr, Gi, wsb[1], Wcr, Wci, W3r, W3i,
                                                 xmag, pmax);
    float* xbuf[5] = {xmag, outS, xmag, outS, xmag};
    for (int i = 0; i < 4; i++) {
        k_conv1f<<<dim3(16, 2, 64), 256, 0, stream>>>(xbuf[i], h2, cw1, bn2g, bn2b, accC2,
                                                      pmax, h1, xbuf[i + 1], accC1, i);
        k_conv2<<<dim3(16, 2, 64), 256, 0, stream>>>(h1, cw2, bn1g, bn1b, accC1, h2,
                                                     accC2, i);
    }
    k9_out<<<65857, 256, 0, stream>>>(xmag, h2, accC2, bn2g, bn2b, Wout, out);
}

// Round 12
// 559.781 us; speedup vs baseline: 1.6737x; 1.6737x over previous
//
#include <hip/hip_runtime.h>
#include <hip/hip_bf16.h>
#include <math.h>

// R10->R11: revert to materialize-once conv dataflow (R6-proven): pure conv1,
// bn1+relu-on-taps conv2, k_res materializes x=relu(x+bn2(h2)) in place, pure k9.
// BN stats: per-b atomic slots (16 contenders max) + shfl-reduce prologue in consumer.
// k2/k4 keep C-prologue (k3 eliminated). 22 launches.

#define NPIX 1048576.f

// ---------------- K0: combined input weights + zero stat slots ----------------
__global__ void k0_prep(const float* __restrict__ Wr, const float* __restrict__ Wi,
                        const float* __restrict__ pr, const float* __restrict__ pi,
                        float* __restrict__ ArT, float* __restrict__ AiT,
                        float* __restrict__ accs) {
    int w  = blockIdx.x;    // 0..63
    int w2 = threadIdx.x;   // 0..255
    float p0r = pr[0], p1r = pr[1], p0i = pi[0], p1i = pi[1];
    float wr0 = Wr[w2 * 64 + w],         wi0 = Wi[w2 * 64 + w];
    float wr1 = Wr[(256 + w2) * 64 + w], wi1 = Wi[(256 + w2) * 64 + w];
    ArT[w * 256 + w2] = p0r * wr0 - p0i * wi0 + p1r * wr1 - p1i * wi1;
    AiT[w * 256 + w2] = p0r * wi0 + p0i * wr0 + p1r * wi1 + p1i * wr1;
    if (w2 < 32) accs[w * 32 + w2] = 0.f;   // aS1[1024] + aS2[1024]
}

// ---------------- K0b: transpose the 8 branch matrices ----------------
__global__ void k0b_T(const float* __restrict__ Wmr, const float* __restrict__ Wmi,
                      float* __restrict__ WmrT, float* __restrict__ WmiT) {
    int m = blockIdx.x;
    int t = threadIdx.x;
    const float* sr = Wmr + m * 4096;
    const float* si = Wmi + m * 4096;
    float* dr = WmrT + m * 4096;
    float* di = WmiT + m * 4096;
    for (int k = t; k < 4096; k += 256) {
        int c = k >> 6, h = k & 63;
        dr[h * 64 + c] = sr[k];
        di[h * 64 + c] = si[k];
    }
}

// ---------------- K1: G projection ----------------
__global__ __launch_bounds__(256) void k1_G(const float* __restrict__ inp,
                                            const float* __restrict__ ArT,
                                            const float* __restrict__ AiT,
                                            float* __restrict__ Gr, float* __restrict__ Gi) {
    int hc = blockIdx.x;
    int b  = blockIdx.y;
    int t  = threadIdx.x;
    __shared__ float sxr[8][64], sxi[8][64];
    int base_r = (b * 2 + 0) * 4096 + hc * 8 * 64;
    int base_i = (b * 2 + 1) * 4096 + hc * 8 * 64;
    for (int k = t; k < 512; k += 256) {
        int r = k >> 6, w = k & 63;
        sxr[r][w] = inp[base_r + r * 64 + w];
        sxi[r][w] = inp[base_i + r * 64 + w];
    }
    __syncthreads();
    float accr[8], acci[8];
#pragma unroll
    for (int r = 0; r < 8; r++) { accr[r] = 0.f; acci[r] = 0.f; }
    for (int k = 0; k < 64; k++) {
        float ar = ArT[k * 256 + t], ai = AiT[k * 256 + t];
#pragma unroll
        for (int r = 0; r < 8; r++) {
            float xr = sxr[r][k], xi = sxi[r][k];
            accr[r] += xr * ar - xi * ai;
            acci[r] += xi * ar + xr * ai;
        }
    }
#pragma unroll
    for (int r = 0; r < 8; r++) {
        int h = hc * 8 + r;
        Gr[(b * 64 + h) * 256 + t] = accr[r];
        Gi[(b * 64 + h) * 256 + t] = acci[r];
    }
}

// ---------------- K2: one branch, C-prologue, 8 rows/thread ----------------
__global__ __launch_bounds__(512) void k2_layer(const float* __restrict__ Gr,
                                                const float* __restrict__ Gi,
                                                const float2* __restrict__ wsumIn,
                                                float2* __restrict__ wsumOut,
                                                const float* __restrict__ Wmr,
                                                const float* __restrict__ Wmi,
                                                const float* __restrict__ WmrT,
                                                const float* __restrict__ WmiT,
                                                const float* __restrict__ Wcr,
                                                const float* __restrict__ Wci,
                                                int layer) {
    int wc = blockIdx.x;  // 4 column chunks of 64
    int j  = blockIdx.y;  // branch
    int b  = blockIdx.z;
    int t = threadIdx.x, tx = t & 63;
    int h0 = __builtin_amdgcn_readfirstlane((t >> 6) << 3);  // 8 rows/wave
    __shared__ float2 sX[4096];   // [h][w] C*G, reused for E
    __shared__ float2 sC[64];

    if (layer == 0) {
        if (t < 64) sC[t] = make_float2(1.f, 0.f);
    } else if (t < 64) {
        float accr = 0.f, acci = 0.f;
#pragma unroll
        for (int jj = 0; jj < 2; jj++) {
            float wr = 0.f, wi = 0.f;
#pragma unroll
            for (int q = 0; q < 4; q++) {
                float2 p = wsumIn[((b * 64 + t) * 2 + jj) * 4 + q];
                wr += p.x; wi += p.y;
            }
            float m2 = wr * wr + wi * wi;
            float cr = 1.f, ci = 0.f;
            if (m2 > 0.f) { float inv = 1.f / sqrtf(m2); cr = wr * inv; ci = -wi * inv; }
            float wcr = Wcr[(layer - 1) * 2 + jj], wci = Wci[(layer - 1) * 2 + jj];
            accr += cr * wcr - ci * wci;
            acci += ci * wcr + cr * wci;
        }
        sC[t] = make_float2(accr, acci);
    }
    __syncthreads();

    int gbase = b * 16384 + wc * 64 + tx;
    float gr_[8], gi_[8];
#pragma unroll
    for (int r = 0; r < 8; r++) {
        int h = h0 + r;
        float gr = Gr[gbase + h * 256], gi = Gi[gbase + h * 256];
        gr_[r] = gr; gi_[r] = gi;
        float2 c = sC[h];
        sX[h * 64 + tx] = make_float2(c.x * gr - c.y * gi, c.x * gi + c.y * gr);
    }
    __syncthreads();

    int mat = layer + 4 * j;
    const float* Wr0  = Wmr  + mat * 4096 + h0 * 64;
    const float* Wi0  = Wmi  + mat * 4096 + h0 * 64;
    const float* WrT0 = WmrT + mat * 4096 + h0 * 64;
    const float* WiT0 = WmiT + mat * 4096 + h0 * 64;

    float Ir[8] = {0,0,0,0,0,0,0,0}, Ii[8] = {0,0,0,0,0,0,0,0};
#pragma unroll 4
    for (int h = 0; h < 64; h++) {
        float2 x = sX[h * 64 + tx];
#pragma unroll
        for (int r = 0; r < 8; r++) {
            float wr = Wr0[r * 64 + h], wi = Wi0[r * 64 + h];
            Ir[r] += wr * x.x - wi * x.y;
            Ii[r] += wr * x.y + wi * x.x;
        }
    }
    __syncthreads();
#pragma unroll
    for (int r = 0; r < 8; r++) {
        float m2 = Ir[r] * Ir[r] + Ii[r] * Ii[r];
        float s = 1.f + __logf(m2);
        sX[(h0 + r) * 64 + tx] = make_float2(s * Ir[r], -s * Ii[r]);
    }
    __syncthreads();

    float Zr[8] = {0,0,0,0,0,0,0,0}, Zi[8] = {0,0,0,0,0,0,0,0};
#pragma unroll 4
    for (int c = 0; c < 64; c++) {
        float2 e = sX[c * 64 + tx];
#pragma unroll
        for (int r = 0; r < 8; r++) {
            float wr = WrT0[r * 64 + c], wi = WiT0[r * 64 + c];
            Zr[r] += wr * e.x - wi * e.y;
            Zi[r] += wr * e.y + wi * e.x;
        }
    }
#pragma unroll
    for (int r = 0; r < 8; r++) {
        int h = h0 + r;
        float pr = gr_[r] * Zr[r] - gi_[r] * Zi[r];
        float pi = gr_[r] * Zi[r] + gi_[r] * Zr[r];
#pragma unroll
        for (int off = 32; off > 0; off >>= 1) {
            pr += __shfl_xor(pr, off);
            pi += __shfl_xor(pi, off);
        }
        if (tx == 0) wsumOut[((b * 64 + h) * 2 + j) * 4 + wc] = make_float2(pr, pi);
    }
}

// ---------------- K4: final projection + block max (C-prologue) ----------------
__global__ __launch_bounds__(1024) void k4_proj(const float* __restrict__ Gr,
                                                const float* __restrict__ Gi,
                                                const float2* __restrict__ wsumIn,
                                                const float* __restrict__ Wcr,
                                                const float* __restrict__ Wci,
                                                const float* __restrict__ W3r,
                                                const float* __restrict__ W3i,
                                                float* __restrict__ xmag,
                                                float* __restrict__ pmax) {
    int wc = blockIdx.x;
    int cb = blockIdx.y;
    int b  = blockIdx.z;
    int t = threadIdx.x, tx = t & 63, ty = t >> 6;
    __shared__ float2 sX[4096];
    __shared__ float2 sC[64];
    if (t < 64) {
        float accr = 0.f, acci = 0.f;
#pragma unroll
        for (int jj = 0; jj < 2; jj++) {
            float wr = 0.f, wi = 0.f;
#pragma unroll
            for (int q = 0; q < 4; q++) {
                float2 p = wsumIn[((b * 64 + t) * 2 + jj) * 4 + q];
                wr += p.x; wi += p.y;
            }
            float m2 = wr * wr + wi * wi;
            float cr = 1.f, ci = 0.f;
            if (m2 > 0.f) { float inv = 1.f / sqrtf(m2); cr = wr * inv; ci = -wi * inv; }
            float wcr = Wcr[6 + jj], wci = Wci[6 + jj];
            accr += cr * wcr - ci * wci;
            acci += ci * wcr + cr * wci;
        }
        sC[t] = make_float2(accr, acci);
    }
    __syncthreads();
    int c0 = __builtin_amdgcn_readfirstlane(ty << 2);
    const float* W3r0 = W3r + (cb * 64 + c0) * 64;
    const float* W3i0 = W3i + (cb * 64 + c0) * 64;
    int gbase = b * 16384 + wc * 64 + tx;
#pragma unroll
    for (int r = 0; r < 4; r++) {
        int h = (ty << 2) + r;
        float gr = Gr[gbase + h * 256], gi = Gi[gbase + h * 256];
        float2 c = sC[h];
        sX[h * 64 + tx] = make_float2(c.x * gr - c.y * gi, c.x * gi + c.y * gr);
    }
    __syncthreads();
    float Fr[4] = {0,0,0,0}, Fi[4] = {0,0,0,0};
#pragma unroll 8
    for (int h = 0; h < 64; h++) {
        float2 x = sX[h * 64 + tx];
#pragma unroll
        for (int r = 0; r < 4; r++) {
            float wr = W3r0[r * 64 + h], wi = W3i0[r * 64 + h];
            Fr[r] += wr * x.x - wi * x.y;
            Fi[r] += wr * x.y + wi * x.x;
        }
    }
    float mx = 0.f;
#pragma unroll
    for (int r = 0; r < 4; r++) {
        int cl = (ty << 2) + r;
        float mag = sqrtf(Fr[r] * Fr[r] + Fi[r] * Fi[r]);
        xmag[(b * 128 + cb * 64 + cl) * 256 + wc * 64 + tx] = mag;
        mx = fmaxf(mx, mag);
    }
#pragma unroll
    for (int off = 32; off > 0; off >>= 1) mx = fmaxf(mx, __shfl_xor(mx, off));
    __syncthreads();
    float* scratch = (float*)sX;
    if (tx == 0) scratch[ty] = mx;
    __syncthreads();
    if (t == 0) {
        float m = scratch[0];
#pragma unroll
        for (int k = 1; k < 16; k++) m = fmaxf(m, scratch[k]);
        pmax[b * 8 + cb * 4 + wc] = m;
    }
}

// ---------------- K5: scale x by 1/max in place ----------------
__global__ void k5b_scale(float* __restrict__ x, const float* __restrict__ pmax) {
    int id = blockIdx.x * 256 + threadIdx.x;
    int b = id >> 15;
    float m = 0.f;
#pragma unroll
    for (int k = 0; k < 8; k++) m = fmaxf(m, pmax[b * 8 + k]);
    x[id] *= 1.f / m;
}

// ---------------- conv1: pure circular conv on materialized x ----------------
__global__ __launch_bounds__(256) void k_conv1(const float* __restrict__ x,
                                               const float* __restrict__ cw,
                                               float* __restrict__ hout,
                                               float* __restrict__ aS1, int layer) {
    int hb = blockIdx.x;  // 8 chunks of 8 rows
    int co = blockIdx.y;
    int b  = blockIdx.z;
    int tx = threadIdx.x;
    float wgt[18];
    const float* wp = cw + layer * 36 + co * 18;
#pragma unroll
    for (int k = 0; k < 18; k++) wgt[k] = wp[k];
    int wm = (tx + 255) & 255, wpp = (tx + 1) & 255;
    float lsum = 0.f, lsq = 0.f;
    for (int r = 0; r < 8; r++) {
        int hh = hb * 8 + r;
        int hm = (hh + 63) & 63, hp = (hh + 1) & 63;
        const int rows[3] = {hm, hh, hp};
        const int cols[3] = {wm, tx, wpp};
        float acc = 0.f;
#pragma unroll
        for (int ci = 0; ci < 2; ci++) {
            const float* xp = x + (b * 2 + ci) * 16384;
            const float* wg = wgt + ci * 9;
#pragma unroll
            for (int kh = 0; kh < 3; kh++)
#pragma unroll
                for (int kw = 0; kw < 3; kw++)
                    acc += wg[kh * 3 + kw] * xp[rows[kh] * 256 + cols[kw]];
        }
        hout[((b * 2 + co) * 64 + hh) * 256 + tx] = acc;
        lsum += acc; lsq += acc * acc;
    }
#pragma unroll
    for (int off = 32; off > 0; off >>= 1) {
        lsum += __shfl_xor(lsum, off);
        lsq  += __shfl_xor(lsq, off);
    }
    __shared__ float ssum[4], ssq[4];
    int tyy = tx >> 6, lane = tx & 63;
    if (lane == 0) { ssum[tyy] = lsum; ssq[tyy] = lsq; }
    __syncthreads();
    if (tx == 0) {
        float s = ssum[0] + ssum[1] + ssum[2] + ssum[3];
        float q = ssq[0] + ssq[1] + ssq[2] + ssq[3];
        atomicAdd(&aS1[(layer * 64 + b) * 4 + co], s);
        atomicAdd(&aS1[(layer * 64 + b) * 4 + 2 + co], q);
    }
}

// ---------------- stats prologue helper (device) ----------------
__device__ inline void bn_stats(const float* __restrict__ aS, const float* __restrict__ g,
                                const float* __restrict__ bb, int layer, int tx,
                                float* __restrict__ st /*LDS[4]*/) {
    if (tx < 64) {
        float s0 = aS[(layer * 64 + tx) * 4 + 0];
        float s1 = aS[(layer * 64 + tx) * 4 + 1];
        float q0 = aS[(layer * 64 + tx) * 4 + 2];
        float q1 = aS[(layer * 64 + tx) * 4 + 3];
#pragma unroll
        for (int off = 32; off > 0; off >>= 1) {
            s0 += __shfl_xor(s0, off); s1 += __shfl_xor(s1, off);
            q0 += __shfl_xor(q0, off); q1 += __shfl_xor(q1, off);
        }
        if (tx == 0) {
            float mu0 = s0 / NPIX, mu1 = s1 / NPIX;
            float rs0 = rsqrtf(q0 / NPIX - mu0 * mu0 + 1e-5f);
            float rs1 = rsqrtf(q1 / NPIX - mu1 * mu1 + 1e-5f);
            float sc0 = rs0 * g[layer * 2 + 0], sc1 = rs1 * g[layer * 2 + 1];
            st[0] = sc0; st[1] = sc1;
            st[2] = bb[layer * 2 + 0] - mu0 * sc0;
            st[3] = bb[layer * 2 + 1] - mu1 * sc1;
        }
    }
}

// ---------------- conv2: bn1+relu on h1 taps ----------------
__global__ __launch_bounds__(256) void k_conv2(const float* __restrict__ h1,
                                               const float* __restrict__ cw,
                                               const float* __restrict__ bn1g,
                                               const float* __restrict__ bn1b,
                                               const float* __restrict__ aS1,
                                               float* __restrict__ hout,
                                               float* __restrict__ aS2, int layer) {
    int hb = blockIdx.x;  // 8 chunks of 8 rows
    int co = blockIdx.y;
    int b  = blockIdx.z;
    int tx = threadIdx.x;
    __shared__ float st[4];
    bn_stats(aS1, bn1g, bn1b, layer, tx, st);
    float wgt[18];
    const float* wp = cw + layer * 36 + co * 18;
#pragma unroll
    for (int k = 0; k < 18; k++) wgt[k] = wp[k];
    __syncthreads();
    float sc0 = st[0], sc1 = st[1], sh0 = st[2], sh1 = st[3];
    int wm = (tx + 255) & 255, wpp = (tx + 1) & 255;
    float lsum = 0.f, lsq = 0.f;
    for (int r = 0; r < 8; r++) {
        int hh = hb * 8 + r;
        int hm = (hh + 63) & 63, hp = (hh + 1) & 63;
        const int rows[3] = {hm, hh, hp};
        const int cols[3] = {wm, tx, wpp};
        float acc = 0.f;
#pragma unroll
        for (int ci = 0; ci < 2; ci++) {
            const float* xp = h1 + (b * 2 + ci) * 16384;
            float sc = ci ? sc1 : sc0, sh = ci ? sh1 : sh0;
            const float* wg = wgt + ci * 9;
#pragma unroll
            for (int kh = 0; kh < 3; kh++)
#pragma unroll
                for (int kw = 0; kw < 3; kw++) {
                    float v = fmaxf(xp[rows[kh] * 256 + cols[kw]] * sc + sh, 0.f);
                    acc += wg[kh * 3 + kw] * v;
                }
        }
        hout[((b * 2 + co) * 64 + hh) * 256 + tx] = acc;
        lsum += acc; lsq += acc * acc;
    }
#pragma unroll
    for (int off = 32; off > 0; off >>= 1) {
        lsum += __shfl_xor(lsum, off);
        lsq  += __shfl_xor(lsq, off);
    }
    __shared__ float ssum[4], ssq[4];
    int tyy = tx >> 6, lane = tx & 63;
    if (lane == 0) { ssum[tyy] = lsum; ssq[tyy] = lsq; }
    __syncthreads();
    if (tx == 0) {
        float s = ssum[0] + ssum[1] + ssum[2] + ssum[3];
        float q = ssq[0] + ssq[1] + ssq[2] + ssq[3];
        atomicAdd(&aS2[(layer * 64 + b) * 4 + co], s);
        atomicAdd(&aS2[(layer * 64 + b) * 4 + 2 + co], q);
    }
}

// ---------------- res: x = relu(x + bn2(h2)) in place ----------------
__global__ __launch_bounds__(256) void k_res(float* __restrict__ x,
                                             const float* __restrict__ h2,
                                             const float* __restrict__ bn2g,
                                             const float* __restrict__ bn2b,
                                             const float* __restrict__ aS2, int layer) {
    int tx = threadIdx.x;
    __shared__ float st[4];
    bn_stats(aS2, bn2g, bn2b, layer, tx, st);
    __syncthreads();
    int id = blockIdx.x * 256 + tx;
    int ch = (id >> 14) & 1;
    float v = x[id] + h2[id] * st[ch] + st[2 + ch];
    x[id] = fmaxf(v, 0.f);
}

// ---------------- K9: pure transposed conv on materialized x ----------------
__global__ void k9_out(const float* __restrict__ x, const float* __restrict__ Wout,
                       float* __restrict__ out) {
    int b  = blockIdx.y;
    int id = blockIdx.x * 256 + threadIdx.x;  // within-b index, 263425
    if (id >= 263425) return;
    int oh = id / 1025;
    int ow = id - oh * 1025;
    int kh0 = (5 - oh) & 3;
    int kw0 = (5 - ow) & 3;
    float acc = 0.f;
#pragma unroll
    for (int ah = 0; ah < 2; ah++) {
        int kh = kh0 + 4 * ah;
        int d = oh + kh - 5;
        if (d < 0 || d > 252) continue;
        int rh = d >> 2;
#pragma unroll
        for (int aw = 0; aw < 2; aw++) {
            int kw = kw0 + 4 * aw;
            int e = ow + kw - 5;
            if (e < 0 || e > 1020) continue;
            int rw = e >> 2;
#pragma unroll
            for (int ci = 0; ci < 2; ci++) {
                float wv = Wout[ci * 64 + (7 - kh) * 8 + (7 - kw)];
                acc += wv * x[((b * 2 + ci) * 64 + rh) * 256 + rw];
            }
        }
    }
    out[b * 263425 + id] = acc;
}

extern "C" void kernel_launch(void* const* d_in, const int* in_sizes, int n_in,
                              void* d_out, int out_size, void* d_ws, size_t ws_size,
                              hipStream_t stream) {
    const float* inp   = (const float*)d_in[0];
    const float* Winr  = (const float*)d_in[1];
    const float* Wini  = (const float*)d_in[2];
    const float* Wprer = (const float*)d_in[3];
    const float* Wprei = (const float*)d_in[4];
    const float* Wmr   = (const float*)d_in[5];
    const float* Wmi   = (const float*)d_in[6];
    const float* Wcr   = (const float*)d_in[7];
    const float* Wci   = (const float*)d_in[8];
    const float* W3r   = (const float*)d_in[9];
    const float* W3i   = (const float*)d_in[10];
    const float* cw1   = (const float*)d_in[11];
    const float* bn1g  = (const float*)d_in[12];
    const float* bn1b  = (const float*)d_in[13];
    const float* cw2   = (const float*)d_in[14];
    const float* bn2g  = (const float*)d_in[15];
    const float* bn2b  = (const float*)d_in[16];
    const float* Wout  = (const float*)d_in[17];
    float* out = (float*)d_out;

    float* ws = (float*)d_ws;
    float*  ArT   = ws;                         // 16384
    float*  AiT   = ArT + 16384;                // 16384
    float*  Gr    = AiT + 16384;                // 1048576
    float*  Gi    = Gr + 1048576;               // 1048576
    float2* wsum0 = (float2*)(Gi + 1048576);    // 32768 f2
    float2* wsum1 = wsum0 + 32768;              // 32768 f2
    float*  xmag  = (float*)(wsum1 + 32768);    // 2097152
    float*  h2    = xmag + 2097152;             // 2097152
    float*  pmax  = h2 + 2097152;               // 512
    float*  aS1   = pmax + 512;                 // 1024
    float*  aS2   = aS1 + 1024;                 // 1024
    float*  h1    = Gr;   // overlay: G dead after k4_proj
    float*  WmrT  = h2;   // overlay: dead before conv2 writes h2
    float*  WmiT  = h2 + 32768;

    k0_prep<<<64, 256, 0, stream>>>(Winr, Wini, Wprer, Wprei, ArT, AiT, aS1);
    k0b_T<<<8, 256, 0, stream>>>(Wmr, Wmi, WmrT, WmiT);
    k1_G<<<dim3(8, 64), 256, 0, stream>>>(inp, ArT, AiT, Gr, Gi);
    float2* wsb[2] = {wsum0, wsum1};
    for (int i = 0; i < 4; i++) {
        k2_layer<<<dim3(4, 2, 64), 512, 0, stream>>>(Gr, Gi, wsb[(i + 1) & 1], wsb[i & 1],
                                                     Wmr, Wmi, WmrT, WmiT, Wcr, Wci, i);
    }
    k4_proj<<<dim3(4, 2, 64), 1024, 0, stream>>>(Gr, Gi, wsb[1], Wcr, Wci, W3r, W3i,
                                                 xmag, pmax);
    k5b_scale<<<8192, 256, 0, stream>>>(xmag, pmax);
    for (int i = 0; i < 4; i++) {
        k_conv1<<<dim3(8, 2, 64), 256, 0, stream>>>(xmag, cw1, h1, aS1, i);
        k_conv2<<<dim3(8, 2, 64), 256, 0, stream>>>(h1, cw2, bn1g, bn1b, aS1, h2, aS2, i);
        k_res<<<8192, 256, 0, stream>>>(xmag, h2, bn2g, bn2b, aS2, i);
    }
    k9_out<<<dim3(1030, 64), 256, 0, stream>>>(xmag, Wout, out);
}